// Round 1
// baseline (1203.072 us; speedup 1.0000x reference)
//
#include <hip/hip_runtime.h>

#define DM 1024
#define HN 16
#define HD 64
#define BB 8
#define LL 512

__device__ __forceinline__ void fma4(float& acc, float4 a, float4 b) {
    acc = fmaf(a.x, b.x, acc);
    acc = fmaf(a.y, b.y, acc);
    acc = fmaf(a.z, b.z, acc);
    acc = fmaf(a.w, b.w, acc);
}

// ---------------- GEMM (f32, 64x64 tile, BK=16) ----------------
// MODE 0: qkv projection. A=[4096,1024] x, W=W_qkv[5120,1024] with col remap
//         (skip unused 'k' chunk rows 1024..2047), scatter to Q/K1/K2/V [B,H,L,hd].
// MODE 1: out projection.  A=[4096,1024] attn_out, W=W_fc[1024,1024], +bias -> C0.
template<int MODE>
__global__ __launch_bounds__(256) void gemm_f32(
    const float* __restrict__ A, const float* __restrict__ W,
    float* __restrict__ C0, float* __restrict__ C1,
    float* __restrict__ C2, float* __restrict__ C3,
    const float* __restrict__ bias)
{
    __shared__ float As[64][20];   // pad 20 floats = 80B rows (16B aligned)
    __shared__ float Ws[64][20];
    const int tid = threadIdx.x;
    const int n0 = blockIdx.x * 64;
    const int m0 = blockIdx.y * 64;
    const int tx = tid & 15, ty = tid >> 4;
    const int lr = tid >> 2, lc = (tid & 3) * 4;

    const int wn = n0 + lr;
    const int wrow = (MODE == 0) ? (wn < 1024 ? wn : wn + 1024) : wn;
    const float* Ap = A + (size_t)(m0 + lr) * DM + lc;
    const float* Wp = W + (size_t)wrow * DM + lc;

    float acc[4][4] = {};
    for (int k0 = 0; k0 < DM; k0 += 16) {
        float4 av = *(const float4*)(Ap + k0);
        float4 wv = *(const float4*)(Wp + k0);
        *(float4*)&As[lr][lc] = av;
        *(float4*)&Ws[lr][lc] = wv;
        __syncthreads();
#pragma unroll
        for (int kk = 0; kk < 16; kk += 4) {
            float4 a4[4], w4[4];
#pragma unroll
            for (int i = 0; i < 4; ++i) a4[i] = *(const float4*)&As[ty * 4 + i][kk];
#pragma unroll
            for (int j = 0; j < 4; ++j) w4[j] = *(const float4*)&Ws[tx + 16 * j][kk];
#pragma unroll
            for (int i = 0; i < 4; ++i)
#pragma unroll
                for (int j = 0; j < 4; ++j) fma4(acc[i][j], a4[i], w4[j]);
        }
        __syncthreads();
    }

    if (MODE == 0) {
        const int c = n0 >> 10;               // 0:q 1:k1 2:k2 3:v
        const int h = (n0 >> 6) & (HN - 1);
        float* T = (c == 0) ? C0 : (c == 1) ? C1 : (c == 2) ? C2 : C3;
#pragma unroll
        for (int i = 0; i < 4; ++i) {
            int m = m0 + ty * 4 + i;
            int b = m >> 9, l = m & (LL - 1);
            size_t base = ((size_t)(b * HN + h) * LL + l) * HD;
#pragma unroll
            for (int j = 0; j < 4; ++j) T[base + tx + 16 * j] = acc[i][j];
        }
    } else {
#pragma unroll
        for (int i = 0; i < 4; ++i) {
            int m = m0 + ty * 4 + i;
#pragma unroll
            for (int j = 0; j < 4; ++j) {
                int n = n0 + tx + 16 * j;
                C0[(size_t)m * DM + n] = acc[i][j] + bias[n];
            }
        }
    }
}

// ---------------- relative sinusoidal PE table [512][64] ----------------
__global__ __launch_bounds__(256) void pe_kernel(float* __restrict__ PE) {
    int idx = blockIdx.x * 256 + threadIdx.x;   // 512*64
    int l = idx >> 6, d = idx & 63;
    float p = (float)(l - LL / 2);              // rel in [-256, 255]
    const float cexp = -9.210340371976184f / 31.0f;  // -ln(10000)/(half-1)
    float val;
    if (d < 32) { float f = expf((float)d * cexp);        val = sinf(p * f); }
    else        { float f = expf((float)(d - 32) * cexp); val = cosf(p * f); }
    PE[idx] = val;
}

// ---------------- pos projection: y = PE @ W_pos^T, split into QP/K1P/K2P [H][L][hd]
__global__ __launch_bounds__(256) void posproj_kernel(
    const float* __restrict__ PE, const float* __restrict__ Wp,
    float* __restrict__ QP, float* __restrict__ K1P, float* __restrict__ K2P)
{
    int idx = blockIdx.x * 256 + threadIdx.x;   // 512*3072
    int l = idx / 3072, e = idx - l * 3072;
    int c = e >> 10, h = (e >> 6) & 15, d = e & 63;
    const float4* pe4 = (const float4*)(PE + (size_t)l * 64);
    const float4* w4  = (const float4*)(Wp + (size_t)e * 64);
    float acc = 0.f;
#pragma unroll
    for (int k = 0; k < 16; ++k) fma4(acc, pe4[k], w4[k]);
    float* T = (c == 0) ? QP : (c == 1) ? K1P : K2P;
    T[((size_t)h * LL + l) * HD + d] = acc;
}

// ---------------- fused attention ----------------
// block = 256 threads, handles (b, h, 32 query rows). Flash-style over 16 key
// tiles of 32. Both self/other dots computed (no divergence), selected by qmask.
__global__ __launch_bounds__(256) void attn_kernel(
    const float* __restrict__ Q, const float* __restrict__ K1,
    const float* __restrict__ K2, const float* __restrict__ V,
    const float* __restrict__ QP, const float* __restrict__ K1P,
    const float* __restrict__ K2P,
    const int* __restrict__ mask, const int* __restrict__ qmask,
    const float* __restrict__ shiftp, const float* __restrict__ biasp,
    float* __restrict__ AO)
{
    __shared__ float Qs[32][68], QPs[32][68];
    __shared__ float K1s[32][68], K2s[32][68], K1Ps[32][68], K2Ps[32][68];
    __shared__ float Ss[32][68];
    __shared__ float Ms[32], Lsum[32], Scs[32];
    __shared__ int qmI[32], qmJ[32], kmJ[32];

    const int tid = threadIdx.x;
    const int bh = blockIdx.x >> 4;
    const int it = blockIdx.x & 15;
    const int b = bh >> 4, h = bh & 15;
    const int i0 = it * 32;

    const float sft = shiftp[0], bia = biasp[0];
    const size_t bh_base = (size_t)(b * HN + h) * LL * HD;
    const size_t h_base  = (size_t)h * LL * HD;

    {   // load Q/QP rows: 512 float4 per tensor over 256 threads
        const float4* Qg  = (const float4*)(Q + bh_base + (size_t)i0 * HD);
        const float4* QPg = (const float4*)(QP + h_base + (size_t)i0 * HD);
        int r0 = tid >> 4, c0 = (tid & 15) * 4;
        *(float4*)&Qs[r0][c0]       = Qg[tid];
        *(float4*)&Qs[16 + r0][c0]  = Qg[tid + 256];
        *(float4*)&QPs[r0][c0]      = QPg[tid];
        *(float4*)&QPs[16 + r0][c0] = QPg[tid + 256];
    }
    if (tid < 32) {
        qmI[tid] = qmask[b * LL + i0 + tid];
        Ms[tid] = -1e30f; Lsum[tid] = 0.f; Scs[tid] = 0.f;
    }

    float O[8] = {};
    const int pr = tid >> 3;           // stats/PV row 0..31
    const int pu = tid & 7;
    const int pd = (tid & 7) * 8;
    const int ry = tid >> 4;           // logit row-pair 0..15
    const int jb = tid & 15;           // logit key base 0..15

    for (int t = 0; t < 16; ++t) {
        const int j0 = t * 32;
        {   // stage K tiles
            const float4* K1g  = (const float4*)(K1 + bh_base + (size_t)j0 * HD);
            const float4* K2g  = (const float4*)(K2 + bh_base + (size_t)j0 * HD);
            const float4* K1Pg = (const float4*)(K1P + h_base + (size_t)j0 * HD);
            const float4* K2Pg = (const float4*)(K2P + h_base + (size_t)j0 * HD);
            int r0 = tid >> 4, c0 = (tid & 15) * 4;
            *(float4*)&K1s[r0][c0]       = K1g[tid];
            *(float4*)&K1s[16 + r0][c0]  = K1g[tid + 256];
            *(float4*)&K2s[r0][c0]       = K2g[tid];
            *(float4*)&K2s[16 + r0][c0]  = K2g[tid + 256];
            *(float4*)&K1Ps[r0][c0]      = K1Pg[tid];
            *(float4*)&K1Ps[16 + r0][c0] = K1Pg[tid + 256];
            *(float4*)&K2Ps[r0][c0]      = K2Pg[tid];
            *(float4*)&K2Ps[16 + r0][c0] = K2Pg[tid + 256];
            if (tid < 32) {
                qmJ[tid] = qmask[b * LL + j0 + tid];
                kmJ[tid] = mask[b * LL + j0 + tid];
            }
        }
        __syncthreads();

        // logits: thread covers rows {2ry,2ry+1} x keys {jb, jb+16}
        float accS[2][2] = {}, accO[2][2] = {};
#pragma unroll
        for (int k4 = 0; k4 < 64; k4 += 4) {
            float4 q0 = *(const float4*)&Qs[2 * ry][k4];
            float4 q1 = *(const float4*)&Qs[2 * ry + 1][k4];
            float4 k1a = *(const float4*)&K1s[jb][k4];
            float4 k1b = *(const float4*)&K1s[jb + 16][k4];
            float4 k2a = *(const float4*)&K2s[jb][k4];
            float4 k2b = *(const float4*)&K2s[jb + 16][k4];
            fma4(accS[0][0], q0, k1a); fma4(accS[0][1], q0, k1b);
            fma4(accS[1][0], q1, k1a); fma4(accS[1][1], q1, k1b);
            fma4(accO[0][0], q0, k2a); fma4(accO[0][1], q0, k2b);
            fma4(accO[1][0], q1, k2a); fma4(accO[1][1], q1, k2b);
        }
#pragma unroll
        for (int k4 = 0; k4 < 64; k4 += 4) {   // positional part
            float4 q0 = *(const float4*)&QPs[2 * ry][k4];
            float4 q1 = *(const float4*)&QPs[2 * ry + 1][k4];
            float4 k1a = *(const float4*)&K1Ps[jb][k4];
            float4 k1b = *(const float4*)&K1Ps[jb + 16][k4];
            float4 k2a = *(const float4*)&K2Ps[jb][k4];
            float4 k2b = *(const float4*)&K2Ps[jb + 16][k4];
            fma4(accS[0][0], q0, k1a); fma4(accS[0][1], q0, k1b);
            fma4(accS[1][0], q1, k1a); fma4(accS[1][1], q1, k1b);
            fma4(accO[0][0], q0, k2a); fma4(accO[0][1], q0, k2b);
            fma4(accO[1][0], q1, k2a); fma4(accO[1][1], q1, k2b);
        }
#pragma unroll
        for (int i = 0; i < 2; ++i)
#pragma unroll
            for (int j = 0; j < 2; ++j) {
                int r = 2 * ry + i, jl = jb + 16 * j;
                float vlog = (qmI[r] == qmJ[jl]) ? accS[i][j] : accO[i][j];
                float di = (float)((i0 + r) - (j0 + jl));
                vlog -= sft * di * di + bia;
                Ss[r][jl] = kmJ[jl] ? vlog : -1e30f;
            }
        __syncthreads();

        {   // stage V into K1s (reused buffer)
            const float4* Vg = (const float4*)(V + bh_base + (size_t)j0 * HD);
            int r0 = tid >> 4, c0 = (tid & 15) * 4;
            float4 v0 = Vg[tid], v1 = Vg[tid + 256];
            *(float4*)&K1s[r0][c0]      = v0;
            *(float4*)&K1s[16 + r0][c0] = v1;
        }
        // online-softmax stats: 8 lanes per row
        float vals[4]; float m4 = -1e30f;
#pragma unroll
        for (int q = 0; q < 4; ++q) { vals[q] = Ss[pr][pu + 8 * q]; m4 = fmaxf(m4, vals[q]); }
        for (int off = 1; off < 8; off <<= 1) m4 = fmaxf(m4, __shfl_xor(m4, off));
        float Mold = Ms[pr];
        float Mn = fmaxf(Mold, m4);
        float sum4 = 0.f;
#pragma unroll
        for (int q = 0; q < 4; ++q) {
            float pv = (vals[q] <= -0.5e30f) ? 0.f : __expf(vals[q] - Mn);
            Ss[pr][pu + 8 * q] = pv;
            sum4 += pv;
        }
        for (int off = 1; off < 8; off <<= 1) sum4 += __shfl_xor(sum4, off);
        float scv = (Mold <= -0.5e30f) ? 0.f : __expf(Mold - Mn);
        if (pu == 0) { Ms[pr] = Mn; Lsum[pr] = Lsum[pr] * scv + sum4; Scs[pr] = scv; }
        __syncthreads();

        // PV: thread owns (row pr, dims pd..pd+7)
        float scp = Scs[pr];
#pragma unroll
        for (int k = 0; k < 8; ++k) O[k] *= scp;
#pragma unroll 8
        for (int j = 0; j < 32; ++j) {
            float p = Ss[pr][j];
            float4 va = *(const float4*)&K1s[j][pd];
            float4 vb = *(const float4*)&K1s[j][pd + 4];
            O[0] = fmaf(p, va.x, O[0]); O[1] = fmaf(p, va.y, O[1]);
            O[2] = fmaf(p, va.z, O[2]); O[3] = fmaf(p, va.w, O[3]);
            O[4] = fmaf(p, vb.x, O[4]); O[5] = fmaf(p, vb.y, O[5]);
            O[6] = fmaf(p, vb.z, O[6]); O[7] = fmaf(p, vb.w, O[7]);
        }
        __syncthreads();
    }

    const float invl = 1.0f / Lsum[pr];
    float* dst = AO + ((size_t)b * LL + (i0 + pr)) * DM + h * HD + pd;
    *(float4*)dst       = make_float4(O[0]*invl, O[1]*invl, O[2]*invl, O[3]*invl);
    *(float4*)(dst + 4) = make_float4(O[4]*invl, O[5]*invl, O[6]*invl, O[7]*invl);
}

extern "C" void kernel_launch(void* const* d_in, const int* in_sizes, int n_in,
                              void* d_out, int out_size, void* d_ws, size_t ws_size,
                              hipStream_t stream) {
    const float* x     = (const float*)d_in[0];
    const int*   mask  = (const int*)d_in[1];
    const int*   qmask = (const int*)d_in[2];
    const float* W_qkv = (const float*)d_in[3];
    const float* W_pos = (const float*)d_in[4];
    const float* W_fc  = (const float*)d_in[5];
    const float* b_fc  = (const float*)d_in[6];
    const float* shift = (const float*)d_in[7];
    const float* bias  = (const float*)d_in[8];
    float* out = (float*)d_out;

    // workspace layout (floats): 90.3 MB total
    float* ws  = (float*)d_ws;
    float* Qw  = ws;                  // [8,16,512,64]
    float* K1w = Qw  + 4194304;
    float* K2w = K1w + 4194304;
    float* Vw  = K2w + 4194304;
    float* QPw = Vw  + 4194304;       // [16,512,64]
    float* K1Pw = QPw + 524288;
    float* K2Pw = K1Pw + 524288;
    float* PEw  = K2Pw + 524288;      // [512,64]
    float* AOw  = PEw + 32768;        // [8,512,1024]

    gemm_f32<0><<<dim3(64, 64), 256, 0, stream>>>(x, W_qkv, Qw, K1w, K2w, Vw, nullptr);
    pe_kernel<<<128, 256, 0, stream>>>(PEw);
    posproj_kernel<<<6144, 256, 0, stream>>>(PEw, W_pos, QPw, K1Pw, K2Pw);
    attn_kernel<<<2048, 256, 0, stream>>>(Qw, K1w, K2w, Vw, QPw, K1Pw, K2Pw,
                                          mask, qmask, shift, bias, AOw);
    gemm_f32<1><<<dim3(16, 64), 256, 0, stream>>>(AOw, W_fc, out, nullptr, nullptr, nullptr, b_fc);
}

// Round 2
// 580.509 us; speedup vs baseline: 2.0724x; 2.0724x over previous
//
#include <hip/hip_runtime.h>

#define DM 1024
#define HN 16
#define HD 64
#define BB 8
#define LL 512

typedef __bf16 bf16x8 __attribute__((ext_vector_type(8)));
typedef float  f32x4  __attribute__((ext_vector_type(4)));

__device__ __forceinline__ void fma4(float& acc, float4 a, float4 b) {
    acc = fmaf(a.x, b.x, acc);
    acc = fmaf(a.y, b.y, acc);
    acc = fmaf(a.z, b.z, acc);
    acc = fmaf(a.w, b.w, acc);
}

// ---------------- f32 -> bf16 conversion (vectorized, 8 elems/thread) ----------------
__global__ __launch_bounds__(256) void cvt_kernel(const float* __restrict__ in,
                                                  __bf16* __restrict__ out, int n8) {
    int i = blockIdx.x * 256 + threadIdx.x;
    if (i >= n8) return;
    const float4* p = (const float4*)in + (size_t)i * 2;
    float4 a = p[0], b = p[1];
    bf16x8 v;
    v[0] = (__bf16)a.x; v[1] = (__bf16)a.y; v[2] = (__bf16)a.z; v[3] = (__bf16)a.w;
    v[4] = (__bf16)b.x; v[5] = (__bf16)b.y; v[6] = (__bf16)b.z; v[7] = (__bf16)b.w;
    ((bf16x8*)out)[i] = v;
}

// ---------------- MFMA bf16 GEMM, m97 structure ----------------
// 128x128 tile, BK=32, 4 waves, each wave 64x64 (4x4 frags of 16x16x32).
// A [M][K] bf16 row-major, B [N][K] bf16 row-major (B^T form). Acc f32.
// MODE 0: scatter C to Q/K1/K2/V f32 [B,H,L,hd].  MODE 1: C0[m][n]=acc+bias[n] f32.
template<int MODE>
__global__ __launch_bounds__(256) void gemm_mfma(
    const __bf16* __restrict__ A, const __bf16* __restrict__ Bm,
    float* __restrict__ C0, float* __restrict__ C1,
    float* __restrict__ C2, float* __restrict__ C3,
    const float* __restrict__ bias, int K)
{
    __shared__ __bf16 As[128 * 32];
    __shared__ __bf16 Bs[128 * 32];
    const int tid = threadIdx.x;
    const int lane = tid & 63;
    const int w = tid >> 6;
    const int wm = w >> 1, wn = w & 1;
    const int n0 = blockIdx.x * 128;
    const int m0 = blockIdx.y * 128;
    const int fr = lane & 15;    // fragment row/col index
    const int fq = lane >> 4;    // quad 0..3

    // staging: thread stages 16B; round r covers rows r*64..r*64+63 of the tile
    const int srow = tid >> 2;            // 0..63
    const int scol = (tid & 3) * 8;
    const __bf16* Ag = A + (size_t)(m0 + srow) * K + scol;
    const __bf16* Bg = Bm + (size_t)(n0 + srow) * K + scol;
    char* AsB = (char*)As + (size_t)w * 1024;   // wave-uniform LDS base (+lane*16 in HW)
    char* BsB = (char*)Bs + (size_t)w * 1024;

    f32x4 acc[4][4] = {};

    for (int k0 = 0; k0 < K; k0 += 32) {
        const __bf16* Agk = Ag + k0;
        const __bf16* Bgk = Bg + k0;
        __builtin_amdgcn_global_load_lds(Agk,                  AsB,        16, 0, 0);
        __builtin_amdgcn_global_load_lds(Agk + (size_t)64 * K, AsB + 4096, 16, 0, 0);
        __builtin_amdgcn_global_load_lds(Bgk,                  BsB,        16, 0, 0);
        __builtin_amdgcn_global_load_lds(Bgk + (size_t)64 * K, BsB + 4096, 16, 0, 0);
        __syncthreads();

        bf16x8 af[4], bfr[4];
#pragma unroll
        for (int i = 0; i < 4; ++i)
            af[i] = *(const bf16x8*)(As + ((size_t)(wm * 64 + i * 16 + fr)) * 32 + fq * 8);
#pragma unroll
        for (int j = 0; j < 4; ++j)
            bfr[j] = *(const bf16x8*)(Bs + ((size_t)(wn * 64 + j * 16 + fr)) * 32 + fq * 8);
#pragma unroll
        for (int i = 0; i < 4; ++i)
#pragma unroll
            for (int j = 0; j < 4; ++j)
                acc[i][j] = __builtin_amdgcn_mfma_f32_16x16x32_bf16(af[i], bfr[j], acc[i][j], 0, 0, 0);
        __syncthreads();
    }

    if (MODE == 0) {
        const int c = n0 >> 10;   // uniform per block (128 | 1024)
        float* T = (c == 0) ? C0 : (c == 1) ? C1 : (c == 2) ? C2 : C3;
#pragma unroll
        for (int i = 0; i < 4; ++i)
#pragma unroll
            for (int j = 0; j < 4; ++j) {
                int ncol = n0 + wn * 64 + j * 16 + fr;
                int h = (ncol >> 6) & 15, d = ncol & 63;
#pragma unroll
                for (int r = 0; r < 4; ++r) {
                    int m = m0 + wm * 64 + i * 16 + fq * 4 + r;
                    int b = m >> 9, l = m & 511;
                    T[((size_t)(b * HN + h) * LL + l) * HD + d] = acc[i][j][r];
                }
            }
    } else {
#pragma unroll
        for (int i = 0; i < 4; ++i)
#pragma unroll
            for (int j = 0; j < 4; ++j) {
                int ncol = n0 + wn * 64 + j * 16 + fr;
                float bv = bias[ncol];
#pragma unroll
                for (int r = 0; r < 4; ++r) {
                    int m = m0 + wm * 64 + i * 16 + fq * 4 + r;
                    C0[(size_t)m * DM + ncol] = acc[i][j][r] + bv;
                }
            }
    }
}

// ---------------- relative sinusoidal PE table [512][64] ----------------
__global__ __launch_bounds__(256) void pe_kernel(float* __restrict__ PE) {
    int idx = blockIdx.x * 256 + threadIdx.x;   // 512*64
    int l = idx >> 6, d = idx & 63;
    float p = (float)(l - LL / 2);
    const float cexp = -9.210340371976184f / 31.0f;  // -ln(10000)/(half-1)
    float val;
    if (d < 32) { float f = expf((float)d * cexp);        val = sinf(p * f); }
    else        { float f = expf((float)(d - 32) * cexp); val = cosf(p * f); }
    PE[idx] = val;
}

// ---------------- pos projection: y = PE @ W_pos^T -> QP/K1P/K2P [H][L][hd] ----------------
__global__ __launch_bounds__(256) void posproj_kernel(
    const float* __restrict__ PE, const float* __restrict__ Wp,
    float* __restrict__ QP, float* __restrict__ K1P, float* __restrict__ K2P)
{
    int idx = blockIdx.x * 256 + threadIdx.x;   // 512*3072
    int l = idx / 3072, e = idx - l * 3072;
    int c = e >> 10, h = (e >> 6) & 15, d = e & 63;
    const float4* pe4 = (const float4*)(PE + (size_t)l * 64);
    const float4* w4  = (const float4*)(Wp + (size_t)e * 64);
    float acc = 0.f;
#pragma unroll
    for (int k = 0; k < 16; ++k) fma4(acc, pe4[k], w4[k]);
    float* T = (c == 0) ? QP : (c == 1) ? K1P : K2P;
    T[((size_t)h * LL + l) * HD + d] = acc;
}

// ---------------- fused attention (f32, flash-style) ----------------
__global__ __launch_bounds__(256) void attn_kernel(
    const float* __restrict__ Q, const float* __restrict__ K1,
    const float* __restrict__ K2, const float* __restrict__ V,
    const float* __restrict__ QP, const float* __restrict__ K1P,
    const float* __restrict__ K2P,
    const int* __restrict__ mask, const int* __restrict__ qmask,
    const float* __restrict__ shiftp, const float* __restrict__ biasp,
    __bf16* __restrict__ AO)
{
    __shared__ float Qs[32][68], QPs[32][68];
    __shared__ float K1s[32][68], K2s[32][68], K1Ps[32][68], K2Ps[32][68];
    __shared__ float Ss[32][68];
    __shared__ float Ms[32], Lsum[32], Scs[32];
    __shared__ int qmI[32], qmJ[32], kmJ[32];

    const int tid = threadIdx.x;
    const int bh = blockIdx.x >> 4;
    const int it = blockIdx.x & 15;
    const int b = bh >> 4, h = bh & 15;
    const int i0 = it * 32;

    const float sft = shiftp[0], bia = biasp[0];
    const size_t bh_base = (size_t)(b * HN + h) * LL * HD;
    const size_t h_base  = (size_t)h * LL * HD;

    {
        const float4* Qg  = (const float4*)(Q + bh_base + (size_t)i0 * HD);
        const float4* QPg = (const float4*)(QP + h_base + (size_t)i0 * HD);
        int r0 = tid >> 4, c0 = (tid & 15) * 4;
        *(float4*)&Qs[r0][c0]       = Qg[tid];
        *(float4*)&Qs[16 + r0][c0]  = Qg[tid + 256];
        *(float4*)&QPs[r0][c0]      = QPg[tid];
        *(float4*)&QPs[16 + r0][c0] = QPg[tid + 256];
    }
    if (tid < 32) {
        qmI[tid] = qmask[b * LL + i0 + tid];
        Ms[tid] = -1e30f; Lsum[tid] = 0.f; Scs[tid] = 0.f;
    }

    float O[8] = {};
    const int pr = tid >> 3;
    const int pu = tid & 7;
    const int pd = (tid & 7) * 8;
    const int ry = tid >> 4;
    const int jb = tid & 15;

    for (int t = 0; t < 16; ++t) {
        const int j0 = t * 32;
        {
            const float4* K1g  = (const float4*)(K1 + bh_base + (size_t)j0 * HD);
            const float4* K2g  = (const float4*)(K2 + bh_base + (size_t)j0 * HD);
            const float4* K1Pg = (const float4*)(K1P + h_base + (size_t)j0 * HD);
            const float4* K2Pg = (const float4*)(K2P + h_base + (size_t)j0 * HD);
            int r0 = tid >> 4, c0 = (tid & 15) * 4;
            *(float4*)&K1s[r0][c0]       = K1g[tid];
            *(float4*)&K1s[16 + r0][c0]  = K1g[tid + 256];
            *(float4*)&K2s[r0][c0]       = K2g[tid];
            *(float4*)&K2s[16 + r0][c0]  = K2g[tid + 256];
            *(float4*)&K1Ps[r0][c0]      = K1Pg[tid];
            *(float4*)&K1Ps[16 + r0][c0] = K1Pg[tid + 256];
            *(float4*)&K2Ps[r0][c0]      = K2Pg[tid];
            *(float4*)&K2Ps[16 + r0][c0] = K2Pg[tid + 256];
            if (tid < 32) {
                qmJ[tid] = qmask[b * LL + j0 + tid];
                kmJ[tid] = mask[b * LL + j0 + tid];
            }
        }
        __syncthreads();

        float accS[2][2] = {}, accO[2][2] = {};
#pragma unroll
        for (int k4 = 0; k4 < 64; k4 += 4) {
            float4 q0 = *(const float4*)&Qs[2 * ry][k4];
            float4 q1 = *(const float4*)&Qs[2 * ry + 1][k4];
            float4 k1a = *(const float4*)&K1s[jb][k4];
            float4 k1b = *(const float4*)&K1s[jb + 16][k4];
            float4 k2a = *(const float4*)&K2s[jb][k4];
            float4 k2b = *(const float4*)&K2s[jb + 16][k4];
            fma4(accS[0][0], q0, k1a); fma4(accS[0][1], q0, k1b);
            fma4(accS[1][0], q1, k1a); fma4(accS[1][1], q1, k1b);
            fma4(accO[0][0], q0, k2a); fma4(accO[0][1], q0, k2b);
            fma4(accO[1][0], q1, k2a); fma4(accO[1][1], q1, k2b);
        }
#pragma unroll
        for (int k4 = 0; k4 < 64; k4 += 4) {
            float4 q0 = *(const float4*)&QPs[2 * ry][k4];
            float4 q1 = *(const float4*)&QPs[2 * ry + 1][k4];
            float4 k1a = *(const float4*)&K1Ps[jb][k4];
            float4 k1b = *(const float4*)&K1Ps[jb + 16][k4];
            float4 k2a = *(const float4*)&K2Ps[jb][k4];
            float4 k2b = *(const float4*)&K2Ps[jb + 16][k4];
            fma4(accS[0][0], q0, k1a); fma4(accS[0][1], q0, k1b);
            fma4(accS[1][0], q1, k1a); fma4(accS[1][1], q1, k1b);
            fma4(accO[0][0], q0, k2a); fma4(accO[0][1], q0, k2b);
            fma4(accO[1][0], q1, k2a); fma4(accO[1][1], q1, k2b);
        }
#pragma unroll
        for (int i = 0; i < 2; ++i)
#pragma unroll
            for (int j = 0; j < 2; ++j) {
                int r = 2 * ry + i, jl = jb + 16 * j;
                float vlog = (qmI[r] == qmJ[jl]) ? accS[i][j] : accO[i][j];
                float di = (float)((i0 + r) - (j0 + jl));
                vlog -= sft * di * di + bia;
                Ss[r][jl] = kmJ[jl] ? vlog : -1e30f;
            }
        __syncthreads();

        {
            const float4* Vg = (const float4*)(V + bh_base + (size_t)j0 * HD);
            int r0 = tid >> 4, c0 = (tid & 15) * 4;
            float4 v0 = Vg[tid], v1 = Vg[tid + 256];
            *(float4*)&K1s[r0][c0]      = v0;
            *(float4*)&K1s[16 + r0][c0] = v1;
        }
        float vals[4]; float m4 = -1e30f;
#pragma unroll
        for (int q = 0; q < 4; ++q) { vals[q] = Ss[pr][pu + 8 * q]; m4 = fmaxf(m4, vals[q]); }
        for (int off = 1; off < 8; off <<= 1) m4 = fmaxf(m4, __shfl_xor(m4, off));
        float Mold = Ms[pr];
        float Mn = fmaxf(Mold, m4);
        float sum4 = 0.f;
#pragma unroll
        for (int q = 0; q < 4; ++q) {
            float pv = (vals[q] <= -0.5e30f) ? 0.f : __expf(vals[q] - Mn);
            Ss[pr][pu + 8 * q] = pv;
            sum4 += pv;
        }
        for (int off = 1; off < 8; off <<= 1) sum4 += __shfl_xor(sum4, off);
        float scv = (Mold <= -0.5e30f) ? 0.f : __expf(Mold - Mn);
        if (pu == 0) { Ms[pr] = Mn; Lsum[pr] = Lsum[pr] * scv + sum4; Scs[pr] = scv; }
        __syncthreads();

        float scp = Scs[pr];
#pragma unroll
        for (int k = 0; k < 8; ++k) O[k] *= scp;
#pragma unroll 8
        for (int j = 0; j < 32; ++j) {
            float p = Ss[pr][j];
            float4 va = *(const float4*)&K1s[j][pd];
            float4 vb = *(const float4*)&K1s[j][pd + 4];
            O[0] = fmaf(p, va.x, O[0]); O[1] = fmaf(p, va.y, O[1]);
            O[2] = fmaf(p, va.z, O[2]); O[3] = fmaf(p, va.w, O[3]);
            O[4] = fmaf(p, vb.x, O[4]); O[5] = fmaf(p, vb.y, O[5]);
            O[6] = fmaf(p, vb.z, O[6]); O[7] = fmaf(p, vb.w, O[7]);
        }
        __syncthreads();
    }

    const float invl = 1.0f / Lsum[pr];
    __bf16* dst = AO + ((size_t)b * LL + (i0 + pr)) * DM + h * HD + pd;
    bf16x8 ov;
#pragma unroll
    for (int k = 0; k < 8; ++k) ov[k] = (__bf16)(O[k] * invl);
    *(bf16x8*)dst = ov;
}

extern "C" void kernel_launch(void* const* d_in, const int* in_sizes, int n_in,
                              void* d_out, int out_size, void* d_ws, size_t ws_size,
                              hipStream_t stream) {
    const float* x     = (const float*)d_in[0];
    const int*   mask  = (const int*)d_in[1];
    const int*   qmask = (const int*)d_in[2];
    const float* W_qkv = (const float*)d_in[3];
    const float* W_pos = (const float*)d_in[4];
    const float* W_fc  = (const float*)d_in[5];
    const float* b_fc  = (const float*)d_in[6];
    const float* shift = (const float*)d_in[7];
    const float* bias  = (const float*)d_in[8];
    float* out = (float*)d_out;

    // workspace layout: exactly 90,308,608 B (same footprint as the passing round-1 layout)
    float* ws  = (float*)d_ws;
    float* Qw  = ws;                        // [8,16,512,64] f32
    float* K1w = Qw  + 4194304;
    float* K2w = K1w + 4194304;
    float* Vw  = K2w + 4194304;
    float* QPw = Vw  + 4194304;             // [16,512,64] f32 x3
    float* K1Pw = QPw + 524288;
    float* K2Pw = K1Pw + 524288;
    float* PEw  = K2Pw + 524288;            // [512,64] f32
    __bf16* Xb    = (__bf16*)(PEw + 32768); // [4096,1024] bf16
    __bf16* Wqkvb = Xb + 4194304;           // [4096,1024] bf16 (remapped rows)
    __bf16* Wfcb  = Wqkvb;                  // alias: cvt runs after gemm<0>
    __bf16* AOb   = Xb;                     // alias: attn writes after gemm<0> read Xb

    cvt_kernel<<<2048, 256, 0, stream>>>(x, Xb, 524288);
    cvt_kernel<<<512, 256, 0, stream>>>(W_qkv, Wqkvb, 131072);                      // q rows 0..1023
    cvt_kernel<<<1536, 256, 0, stream>>>(W_qkv + 2097152, Wqkvb + 1048576, 393216); // k1,k2,v rows 2048..5119
    gemm_mfma<0><<<dim3(32, 32), 256, 0, stream>>>(Xb, Wqkvb, Qw, K1w, K2w, Vw, nullptr, 1024);
    cvt_kernel<<<512, 256, 0, stream>>>(W_fc, Wfcb, 131072);
    pe_kernel<<<128, 256, 0, stream>>>(PEw);
    posproj_kernel<<<6144, 256, 0, stream>>>(PEw, W_pos, QPw, K1Pw, K2Pw);
    attn_kernel<<<2048, 256, 0, stream>>>(Qw, K1w, K2w, Vw, QPw, K1Pw, K2Pw,
                                          mask, qmask, shift, bias, AOb);
    gemm_mfma<1><<<dim3(8, 32), 256, 0, stream>>>(AOb, Wfcb, out, nullptr, nullptr, nullptr, b_fc, 1024);
}

// Round 3
// 233.861 us; speedup vs baseline: 5.1444x; 2.4823x over previous
//
#include <hip/hip_runtime.h>

#define DM 1024
#define HN 16
#define HD 64
#define BB 8
#define LL 512

typedef __bf16 bf16x8 __attribute__((ext_vector_type(8)));
typedef __bf16 bf16x4 __attribute__((ext_vector_type(4)));
typedef float  f32x4  __attribute__((ext_vector_type(4)));

__device__ __forceinline__ void fma4(float& acc, float4 a, float4 b) {
    acc = fmaf(a.x, b.x, acc);
    acc = fmaf(a.y, b.y, acc);
    acc = fmaf(a.z, b.z, acc);
    acc = fmaf(a.w, b.w, acc);
}

// ---------------- f32 -> bf16 conversion ----------------
__global__ __launch_bounds__(256) void cvt_kernel(const float* __restrict__ in,
                                                  __bf16* __restrict__ out, int n8) {
    int i = blockIdx.x * 256 + threadIdx.x;
    if (i >= n8) return;
    const float4* p = (const float4*)in + (size_t)i * 2;
    float4 a = p[0], b = p[1];
    bf16x8 v;
    v[0] = (__bf16)a.x; v[1] = (__bf16)a.y; v[2] = (__bf16)a.z; v[3] = (__bf16)a.w;
    v[4] = (__bf16)b.x; v[5] = (__bf16)b.y; v[6] = (__bf16)b.z; v[7] = (__bf16)b.w;
    ((bf16x8*)out)[i] = v;
}

// ---------------- MFMA bf16 GEMM (m97 structure) ----------------
// MODE 0: qkv proj -> bf16 concat layouts: Qc/K1c/K2c [b,h,l,128] (cols 0..63),
//         Vn [b,h,l,64].  MODE 1: outF[m][n] = acc + bias[n] (f32).
template<int MODE>
__global__ __launch_bounds__(256) void gemm_mfma(
    const __bf16* __restrict__ A, const __bf16* __restrict__ Bm,
    __bf16* __restrict__ Qc, __bf16* __restrict__ K1c,
    __bf16* __restrict__ K2c, __bf16* __restrict__ Vn,
    float* __restrict__ outF, const float* __restrict__ bias, int K)
{
    __shared__ __bf16 As[128 * 32];
    __shared__ __bf16 Bs[128 * 32];
    const int tid = threadIdx.x;
    const int lane = tid & 63;
    const int w = tid >> 6;
    const int wm = w >> 1, wn = w & 1;
    const int n0 = blockIdx.x * 128;
    const int m0 = blockIdx.y * 128;
    const int fr = lane & 15;
    const int fq = lane >> 4;

    const int srow = tid >> 2;
    const int scol = (tid & 3) * 8;
    const __bf16* Ag = A + (size_t)(m0 + srow) * K + scol;
    const __bf16* Bg = Bm + (size_t)(n0 + srow) * K + scol;
    char* AsB = (char*)As + (size_t)w * 1024;
    char* BsB = (char*)Bs + (size_t)w * 1024;

    f32x4 acc[4][4] = {};

    for (int k0 = 0; k0 < K; k0 += 32) {
        const __bf16* Agk = Ag + k0;
        const __bf16* Bgk = Bg + k0;
        __builtin_amdgcn_global_load_lds(Agk,                  AsB,        16, 0, 0);
        __builtin_amdgcn_global_load_lds(Agk + (size_t)64 * K, AsB + 4096, 16, 0, 0);
        __builtin_amdgcn_global_load_lds(Bgk,                  BsB,        16, 0, 0);
        __builtin_amdgcn_global_load_lds(Bgk + (size_t)64 * K, BsB + 4096, 16, 0, 0);
        __syncthreads();

        bf16x8 af[4], bfr[4];
#pragma unroll
        for (int i = 0; i < 4; ++i)
            af[i] = *(const bf16x8*)(As + ((size_t)(wm * 64 + i * 16 + fr)) * 32 + fq * 8);
#pragma unroll
        for (int j = 0; j < 4; ++j)
            bfr[j] = *(const bf16x8*)(Bs + ((size_t)(wn * 64 + j * 16 + fr)) * 32 + fq * 8);
#pragma unroll
        for (int i = 0; i < 4; ++i)
#pragma unroll
            for (int j = 0; j < 4; ++j)
                acc[i][j] = __builtin_amdgcn_mfma_f32_16x16x32_bf16(af[i], bfr[j], acc[i][j], 0, 0, 0);
        __syncthreads();
    }

    if (MODE == 0) {
        const int c = n0 >> 10;   // 0:q 1:k1 2:k2 3:v (uniform per block)
#pragma unroll
        for (int i = 0; i < 4; ++i)
#pragma unroll
            for (int j = 0; j < 4; ++j) {
                int ncol = n0 + wn * 64 + j * 16 + fr;
                int e = ncol & 1023, h = e >> 6, d = e & 63;
#pragma unroll
                for (int r = 0; r < 4; ++r) {
                    int m = m0 + wm * 64 + i * 16 + fq * 4 + r;
                    int b = m >> 9, l = m & 511;
                    __bf16 val = (__bf16)acc[i][j][r];
                    size_t bh = (size_t)(b * HN + h);
                    if (c == 0)      Qc [(bh * LL + l) * 128 + d] = val;
                    else if (c == 1) K1c[(bh * LL + l) * 128 + d] = val;
                    else if (c == 2) K2c[(bh * LL + l) * 128 + d] = val;
                    else             Vn [(bh * LL + l) * 64  + d] = val;
                }
            }
    } else {
#pragma unroll
        for (int i = 0; i < 4; ++i)
#pragma unroll
            for (int j = 0; j < 4; ++j) {
                int ncol = n0 + wn * 64 + j * 16 + fr;
                float bv = bias[ncol];
#pragma unroll
                for (int r = 0; r < 4; ++r) {
                    int m = m0 + wm * 64 + i * 16 + fq * 4 + r;
                    outF[(size_t)m * DM + ncol] = acc[i][j][r] + bv;
                }
            }
    }
}

// ---------------- V transpose: Vn[b,h,l,64] -> Vt[b,h,d,512] (bf16) ----------------
__global__ __launch_bounds__(256) void vtrans_kernel(const __bf16* __restrict__ Vn,
                                                     __bf16* __restrict__ Vt) {
    __shared__ __bf16 Ts[64][72];
    int bh = blockIdx.x >> 3, lt = blockIdx.x & 7;
    const __bf16* src = Vn + ((size_t)bh * LL + lt * 64) * 64;
    int r = threadIdx.x >> 2, s = threadIdx.x & 3;
    *(bf16x8*)&Ts[r][s * 16]     = *(const bf16x8*)(src + r * 64 + s * 16);
    *(bf16x8*)&Ts[r][s * 16 + 8] = *(const bf16x8*)(src + r * 64 + s * 16 + 8);
    __syncthreads();
    __bf16* dst = Vt + ((size_t)bh * 64 + r) * LL + lt * 64 + s * 16;
    bf16x8 a, bvv;
#pragma unroll
    for (int e = 0; e < 8; ++e) { a[e] = Ts[s * 16 + e][r]; bvv[e] = Ts[s * 16 + 8 + e][r]; }
    *(bf16x8*)dst = a;
    *(bf16x8*)(dst + 8) = bvv;
}

// ---------------- relative sinusoidal PE table [512][64] ----------------
__global__ __launch_bounds__(256) void pe_kernel(float* __restrict__ PE) {
    int idx = blockIdx.x * 256 + threadIdx.x;
    int l = idx >> 6, d = idx & 63;
    float p = (float)(l - LL / 2);
    const float cexp = -9.210340371976184f / 31.0f;
    float val;
    if (d < 32) { float f = expf((float)d * cexp);        val = sinf(p * f); }
    else        { float f = expf((float)(d - 32) * cexp); val = cosf(p * f); }
    PE[idx] = val;
}

// ---------------- pos projection -> bf16 cols 64..127 of Qc/K1c/K2c, all 8 b ----------------
__global__ __launch_bounds__(256) void posproj_kernel(
    const float* __restrict__ PE, const float* __restrict__ Wp,
    __bf16* __restrict__ Qc, __bf16* __restrict__ K1c, __bf16* __restrict__ K2c)
{
    int idx = blockIdx.x * 256 + threadIdx.x;   // 512*3072
    int l = idx / 3072, e = idx - l * 3072;
    int c = e >> 10, h = (e >> 6) & 15, d = e & 63;
    const float4* pe4 = (const float4*)(PE + (size_t)l * 64);
    const float4* w4  = (const float4*)(Wp + (size_t)e * 64);
    float acc = 0.f;
#pragma unroll
    for (int k = 0; k < 16; ++k) fma4(acc, pe4[k], w4[k]);
    __bf16 bv = (__bf16)acc;
    __bf16* T = (c == 0) ? Qc : (c == 1) ? K1c : K2c;
    size_t off = ((size_t)h * LL + l) * 128 + 64 + d;
#pragma unroll
    for (int b = 0; b < 8; ++b) T[(size_t)b * (HN * LL * 128) + off] = bv;
}

// ---------------- MFMA flash attention ----------------
// block = 256 thr (4 waves), grid = (b,h,qt): qt*128 q-rows; wave: 32 q (jq=0,1).
// Swapped QK^T: S^T = mfma(K, Q) -> lane holds S[key=fq*4+r + 16*kb][q=fr].
// Online softmax lane-local in q; PV via O^T = mfma(Vt, P) (P through LDS).
__global__ __launch_bounds__(256) void attn_kernel(
    const __bf16* __restrict__ Qc, const __bf16* __restrict__ K1c,
    const __bf16* __restrict__ K2c, const __bf16* __restrict__ Vt,
    const int* __restrict__ maskp, const int* __restrict__ qmask,
    const float* __restrict__ shiftp, const float* __restrict__ biasp,
    __bf16* __restrict__ AO)
{
    __shared__ __bf16 K1s[64 * 136];   // padded stride 136 bf16 = 272B (16B-aligned)
    __shared__ __bf16 K2s[64 * 136];
    __shared__ __bf16 Vts[64 * 72];    // stride 72 bf16 = 144B
    __shared__ __bf16 Sb[4 * 16 * 72]; // P staging, 16 rows per wave

    const int tid = threadIdx.x;
    const int lane = tid & 63;
    const int wid = tid >> 6;
    const int fr = lane & 15;
    const int fq = lane >> 4;

    const int qt = blockIdx.x & 3;
    const int h  = (blockIdx.x >> 2) & 15;
    const int b  = blockIdx.x >> 6;
    const int q0w = qt * 128 + wid * 32;
    const size_t bh = (size_t)(b * HN + h);

    const float sft = shiftp[0], bia = biasp[0];

    // Q fragments (registers, reused across all KV tiles): B-operand layout
    bf16x8 qf[2][4];
#pragma unroll
    for (int jq = 0; jq < 2; ++jq)
#pragma unroll
        for (int kf = 0; kf < 4; ++kf)
            qf[jq][kf] = *(const bf16x8*)(Qc + (bh * LL + q0w + jq * 16 + fr) * 128 + kf * 32 + fq * 8);

    const int qmI[2] = { qmask[b * LL + q0w + fr], qmask[b * LL + q0w + 16 + fr] };
    const float qgf[2] = { (float)(q0w + fr), (float)(q0w + 16 + fr) };

    float mrun[2] = { -1e30f, -1e30f };
    float lrun[2] = { 0.f, 0.f };
    f32x4 ot[4][2] = {};   // O^T[d=fd*16+fq*4+r][q=jq*16+fr]

    const __bf16* K1g0 = K1c + bh * LL * 128;
    const __bf16* K2g0 = K2c + bh * LL * 128;
    const __bf16* Vtg0 = Vt + bh * 64 * LL;
    __bf16* Sw = Sb + wid * 16 * 72;

    for (int t = 0; t < 8; ++t) {
        const int j0 = t * 64;
        // ---- stage K1/K2 (64x128 bf16 each) and Vt (64 d x 64 keys) ----
        const __bf16* K1g = K1g0 + (size_t)j0 * 128;
        const __bf16* K2g = K2g0 + (size_t)j0 * 128;
#pragma unroll
        for (int p = 0; p < 4; ++p) {
            int idx = p * 256 + tid, rr = idx >> 4, u = idx & 15;
            *(bf16x8*)(K1s + rr * 136 + u * 8) = *(const bf16x8*)(K1g + rr * 128 + u * 8);
            *(bf16x8*)(K2s + rr * 136 + u * 8) = *(const bf16x8*)(K2g + rr * 128 + u * 8);
        }
#pragma unroll
        for (int p = 0; p < 2; ++p) {
            int idx = p * 256 + tid, rr = idx >> 3, u = idx & 7;
            *(bf16x8*)(Vts + rr * 72 + u * 8) = *(const bf16x8*)(Vtg0 + (size_t)rr * LL + j0 + u * 8);
        }
        unsigned long long qbits = __ballot(qmask[b * LL + j0 + lane] != 0);
        unsigned long long kbits = __ballot(maskp[b * LL + j0 + lane] != 0);
        __syncthreads();

        // ---- QK^T (self) ----
        f32x4 accS[4][2] = {};
#pragma unroll
        for (int kb = 0; kb < 4; ++kb) {
            bf16x8 af[4];
#pragma unroll
            for (int kf = 0; kf < 4; ++kf)
                af[kf] = *(const bf16x8*)(K1s + (kb * 16 + fr) * 136 + kf * 32 + fq * 8);
#pragma unroll
            for (int kf = 0; kf < 4; ++kf) {
                accS[kb][0] = __builtin_amdgcn_mfma_f32_16x16x32_bf16(af[kf], qf[0][kf], accS[kb][0], 0, 0, 0);
                accS[kb][1] = __builtin_amdgcn_mfma_f32_16x16x32_bf16(af[kf], qf[1][kf], accS[kb][1], 0, 0, 0);
            }
        }
        // ---- QK^T (other) + fused select/gaussian/mask ----
#pragma unroll
        for (int kb = 0; kb < 4; ++kb) {
            bf16x8 af[4];
#pragma unroll
            for (int kf = 0; kf < 4; ++kf)
                af[kf] = *(const bf16x8*)(K2s + (kb * 16 + fr) * 136 + kf * 32 + fq * 8);
            f32x4 accO[2] = {};
#pragma unroll
            for (int kf = 0; kf < 4; ++kf) {
                accO[0] = __builtin_amdgcn_mfma_f32_16x16x32_bf16(af[kf], qf[0][kf], accO[0], 0, 0, 0);
                accO[1] = __builtin_amdgcn_mfma_f32_16x16x32_bf16(af[kf], qf[1][kf], accO[1], 0, 0, 0);
            }
#pragma unroll
            for (int jq = 0; jq < 2; ++jq)
#pragma unroll
                for (int r = 0; r < 4; ++r) {
                    int ko = kb * 16 + fq * 4 + r;
                    float v = (((int)(qbits >> ko) & 1) == qmI[jq]) ? accS[kb][jq][r] : accO[jq][r];
                    float di = qgf[jq] - (float)(j0 + ko);
                    v = v - fmaf(sft, di * di, bia);
                    accS[kb][jq][r] = ((int)(kbits >> ko) & 1) ? v : -1e30f;
                }
        }

        // ---- online softmax (q lane-local) ----
        float mn0 = mrun[0], mn1 = mrun[1];
#pragma unroll
        for (int kb = 0; kb < 4; ++kb)
#pragma unroll
            for (int r = 0; r < 4; ++r) {
                mn0 = fmaxf(mn0, accS[kb][0][r]);
                mn1 = fmaxf(mn1, accS[kb][1][r]);
            }
        mn0 = fmaxf(mn0, __shfl_xor(mn0, 16)); mn0 = fmaxf(mn0, __shfl_xor(mn0, 32));
        mn1 = fmaxf(mn1, __shfl_xor(mn1, 16)); mn1 = fmaxf(mn1, __shfl_xor(mn1, 32));
        float sc0 = __expf(mrun[0] - mn0), sc1 = __expf(mrun[1] - mn1);
        mrun[0] = mn0; mrun[1] = mn1;
        float sum0 = 0.f, sum1 = 0.f;
#pragma unroll
        for (int kb = 0; kb < 4; ++kb)
#pragma unroll
            for (int r = 0; r < 4; ++r) {
                float p0 = __expf(accS[kb][0][r] - mn0);
                float p1 = __expf(accS[kb][1][r] - mn1);
                accS[kb][0][r] = p0; accS[kb][1][r] = p1;
                sum0 += p0; sum1 += p1;
            }
        sum0 += __shfl_xor(sum0, 16); sum0 += __shfl_xor(sum0, 32);
        sum1 += __shfl_xor(sum1, 16); sum1 += __shfl_xor(sum1, 32);
        lrun[0] = lrun[0] * sc0 + sum0;
        lrun[1] = lrun[1] * sc1 + sum1;
#pragma unroll
        for (int fd = 0; fd < 4; ++fd)
#pragma unroll
            for (int r = 0; r < 4; ++r) { ot[fd][0][r] *= sc0; ot[fd][1][r] *= sc1; }

        // ---- PV: O^T += mfma(Vt, P) ----
        bf16x8 vtf[4][2];
#pragma unroll
        for (int fd = 0; fd < 4; ++fd)
#pragma unroll
            for (int kf = 0; kf < 2; ++kf)
                vtf[fd][kf] = *(const bf16x8*)(Vts + (fd * 16 + fr) * 72 + kf * 32 + fq * 8);
#pragma unroll
        for (int jq = 0; jq < 2; ++jq) {
#pragma unroll
            for (int kb = 0; kb < 4; ++kb) {
                bf16x4 pk;
#pragma unroll
                for (int r = 0; r < 4; ++r) pk[r] = (__bf16)accS[kb][jq][r];
                *(bf16x4*)(Sw + fr * 72 + kb * 16 + fq * 4) = pk;
            }
            bf16x8 pf0 = *(const bf16x8*)(Sw + fr * 72 + fq * 8);
            bf16x8 pf1 = *(const bf16x8*)(Sw + fr * 72 + 32 + fq * 8);
#pragma unroll
            for (int fd = 0; fd < 4; ++fd) {
                ot[fd][jq] = __builtin_amdgcn_mfma_f32_16x16x32_bf16(vtf[fd][0], pf0, ot[fd][jq], 0, 0, 0);
                ot[fd][jq] = __builtin_amdgcn_mfma_f32_16x16x32_bf16(vtf[fd][1], pf1, ot[fd][jq], 0, 0, 0);
            }
        }
        __syncthreads();
    }

    // ---- epilogue: AO[b, q, h*64+d] = O^T * (1/l)  (bf16) ----
#pragma unroll
    for (int jq = 0; jq < 2; ++jq) {
        float inv = 1.0f / lrun[jq];
        int q = q0w + jq * 16 + fr;
        __bf16* dst = AO + ((size_t)(b * LL + q)) * DM + h * 64;
#pragma unroll
        for (int fd = 0; fd < 4; ++fd) {
            bf16x4 o;
#pragma unroll
            for (int r = 0; r < 4; ++r) o[r] = (__bf16)(ot[fd][jq][r] * inv);
            *(bf16x4*)(dst + fd * 16 + fq * 4) = o;
        }
    }
}

extern "C" void kernel_launch(void* const* d_in, const int* in_sizes, int n_in,
                              void* d_out, int out_size, void* d_ws, size_t ws_size,
                              hipStream_t stream) {
    const float* x     = (const float*)d_in[0];
    const int*   mask  = (const int*)d_in[1];
    const int*   qmask = (const int*)d_in[2];
    const float* W_qkv = (const float*)d_in[3];
    const float* W_pos = (const float*)d_in[4];
    const float* W_fc  = (const float*)d_in[5];
    const float* b_fc  = (const float*)d_in[6];
    const float* shift = (const float*)d_in[7];
    const float* bias  = (const float*)d_in[8];
    float* out = (float*)d_out;

    // workspace (84.0 MB, fits prior 90.3 MB footprint)
    __bf16* Qcb  = (__bf16*)d_ws;           // [8,16,512,128]
    __bf16* K1cb = Qcb  + 8388608;
    __bf16* K2cb = K1cb + 8388608;
    __bf16* Vnb  = K2cb + 8388608;          // [8,16,512,64]
    __bf16* Vtb  = Vnb  + 4194304;          // [8,16,64,512]
    __bf16* Xb   = Vtb  + 4194304;          // [4096,1024]
    __bf16* Wqkvb = Xb  + 4194304;          // [4096,1024] remapped
    __bf16* Wfcb  = Wqkvb;                  // alias (cvt after gemm0)
    __bf16* AOb   = Xb;                     // alias (attn after gemm0)
    float*  PEw   = (float*)(Wqkvb + 4194304);  // [512,64] f32

    cvt_kernel<<<2048, 256, 0, stream>>>(x, Xb, 524288);
    cvt_kernel<<<512, 256, 0, stream>>>(W_qkv, Wqkvb, 131072);
    cvt_kernel<<<1536, 256, 0, stream>>>(W_qkv + 2097152, Wqkvb + 1048576, 393216);
    gemm_mfma<0><<<dim3(32, 32), 256, 0, stream>>>(Xb, Wqkvb, Qcb, K1cb, K2cb, Vnb,
                                                   nullptr, nullptr, 1024);
    vtrans_kernel<<<1024, 256, 0, stream>>>(Vnb, Vtb);
    cvt_kernel<<<512, 256, 0, stream>>>(W_fc, Wfcb, 131072);
    pe_kernel<<<128, 256, 0, stream>>>(PEw);
    posproj_kernel<<<6144, 256, 0, stream>>>(PEw, W_pos, Qcb, K1cb, K2cb);
    attn_kernel<<<512, 256, 0, stream>>>(Qcb, K1cb, K2cb, Vtb, mask, qmask,
                                         shift, bias, AOb);
    gemm_mfma<1><<<dim3(8, 32), 256, 0, stream>>>(AOb, Wfcb, nullptr, nullptr, nullptr,
                                                  nullptr, out, b_fc, 1024);
}

// Round 4
// 221.071 us; speedup vs baseline: 5.4420x; 1.0579x over previous
//
#include <hip/hip_runtime.h>

#define DM 1024
#define HN 16
#define HD 64
#define BB 8
#define LL 512

typedef __bf16 bf16x8 __attribute__((ext_vector_type(8)));
typedef __bf16 bf16x4 __attribute__((ext_vector_type(4)));
typedef float  f32x4  __attribute__((ext_vector_type(4)));

__device__ __forceinline__ void fma4(float& acc, float4 a, float4 b) {
    acc = fmaf(a.x, b.x, acc);
    acc = fmaf(a.y, b.y, acc);
    acc = fmaf(a.z, b.z, acc);
    acc = fmaf(a.w, b.w, acc);
}

// ---------------- f32 -> bf16 conversion ----------------
__global__ __launch_bounds__(256) void cvt_kernel(const float* __restrict__ in,
                                                  __bf16* __restrict__ out, int n8) {
    int i = blockIdx.x * 256 + threadIdx.x;
    if (i >= n8) return;
    const float4* p = (const float4*)in + (size_t)i * 2;
    float4 a = p[0], b = p[1];
    bf16x8 v;
    v[0] = (__bf16)a.x; v[1] = (__bf16)a.y; v[2] = (__bf16)a.z; v[3] = (__bf16)a.w;
    v[4] = (__bf16)b.x; v[5] = (__bf16)b.y; v[6] = (__bf16)b.z; v[7] = (__bf16)b.w;
    ((bf16x8*)out)[i] = v;
}

// ---------------- MFMA bf16 GEMM (m97 structure + src-swizzle + staged epilogue) ----
// Swapped operands: acc = mfma(Bfrag, Afrag) -> thread holds n-contiguous quad:
//   m = wm*64+i*16+fr (lane col), n = wn*64+j*16+fq*4+r (row=reg).
// MODE 0: qkv proj -> bf16: Qc/K1c/K2c [b,h,l,128] (cols 0..63), Vn [b,h,l,64].
// MODE 1: outF[m][n] = acc + bias[n] (f32), direct float4 stores.
template<int MODE>
__global__ __launch_bounds__(256) void gemm_mfma(
    const __bf16* __restrict__ A, const __bf16* __restrict__ Bm,
    __bf16* __restrict__ Qc, __bf16* __restrict__ K1c,
    __bf16* __restrict__ K2c, __bf16* __restrict__ Vn,
    float* __restrict__ outF, const float* __restrict__ bias, int K)
{
    __shared__ __bf16 As[128 * 32];
    __shared__ __bf16 Bs[128 * 32];
    const int tid = threadIdx.x;
    const int lane = tid & 63;
    const int w = tid >> 6;
    const int wm = w >> 1, wn = w & 1;
    const int n0 = blockIdx.x * 128;
    const int m0 = blockIdx.y * 128;
    const int fr = lane & 15;
    const int fq = lane >> 4;

    // staging with source-side chunk swizzle (LDS stays linear; rule #21)
    const int srow = tid >> 2;                       // 0..63
    const int schs = (tid & 3) ^ ((srow >> 1) & 3);  // swizzled 16B chunk
    const __bf16* Ag = A + (size_t)(m0 + srow) * K + schs * 8;
    const __bf16* Bg = Bm + (size_t)(n0 + srow) * K + schs * 8;
    char* AsB = (char*)As + (size_t)w * 1024;
    char* BsB = (char*)Bs + (size_t)w * 1024;

    const int fsl = fq ^ ((fr >> 1) & 3);            // swizzled read slot

    f32x4 acc[4][4] = {};

    for (int k0 = 0; k0 < K; k0 += 32) {
        const __bf16* Agk = Ag + k0;
        const __bf16* Bgk = Bg + k0;
        __builtin_amdgcn_global_load_lds(Agk,                  AsB,        16, 0, 0);
        __builtin_amdgcn_global_load_lds(Agk + (size_t)64 * K, AsB + 4096, 16, 0, 0);
        __builtin_amdgcn_global_load_lds(Bgk,                  BsB,        16, 0, 0);
        __builtin_amdgcn_global_load_lds(Bgk + (size_t)64 * K, BsB + 4096, 16, 0, 0);
        __syncthreads();

        bf16x8 af[4], bfr[4];
#pragma unroll
        for (int i = 0; i < 4; ++i)
            af[i] = *(const bf16x8*)(As + (size_t)(wm * 64 + i * 16 + fr) * 32 + fsl * 8);
#pragma unroll
        for (int j = 0; j < 4; ++j)
            bfr[j] = *(const bf16x8*)(Bs + (size_t)(wn * 64 + j * 16 + fr) * 32 + fsl * 8);
#pragma unroll
        for (int i = 0; i < 4; ++i)
#pragma unroll
            for (int j = 0; j < 4; ++j)
                acc[i][j] = __builtin_amdgcn_mfma_f32_16x16x32_bf16(bfr[j], af[i], acc[i][j], 0, 0, 0);
        __syncthreads();
    }

    if constexpr (MODE == 0) {
        __shared__ __bf16 Cs[128 * 136];   // [m][n], n-stride 136
#pragma unroll
        for (int i = 0; i < 4; ++i) {
            int mloc = wm * 64 + i * 16 + fr;
#pragma unroll
            for (int j = 0; j < 4; ++j) {
                int nloc = wn * 64 + j * 16 + fq * 4;
                bf16x4 v;
#pragma unroll
                for (int r = 0; r < 4; ++r) v[r] = (__bf16)acc[i][j][r];
                *(bf16x4*)(Cs + (size_t)mloc * 136 + nloc) = v;
            }
        }
        __syncthreads();
        const int c = n0 >> 10;   // 0:q 1:k1 2:k2 3:v (block-uniform)
        __bf16* T = (c == 0) ? Qc : (c == 1) ? K1c : (c == 2) ? K2c : Vn;
        const int b = m0 >> 9, l0 = m0 & 511, h0 = (n0 >> 6) & 15;
#pragma unroll
        for (int rnd = 0; rnd < 8; ++rnd) {
            int Ci = rnd * 256 + tid;
            int m = Ci >> 4, nch = Ci & 15;
            bf16x8 v = *(const bf16x8*)(Cs + (size_t)m * 136 + nch * 8);
            int hl = nch >> 3, d = (nch & 7) * 8;
            size_t bh2 = (size_t)(b * HN + h0 + hl);
            if (c < 3) *(bf16x8*)(T + (bh2 * LL + l0 + m) * 128 + d) = v;
            else       *(bf16x8*)(T + (bh2 * LL + l0 + m) * 64  + d) = v;
        }
    } else {
#pragma unroll
        for (int i = 0; i < 4; ++i) {
            int m = m0 + wm * 64 + i * 16 + fr;
#pragma unroll
            for (int j = 0; j < 4; ++j) {
                int nn = n0 + wn * 64 + j * 16 + fq * 4;
                float4 bv = *(const float4*)(bias + nn);
                *(float4*)(outF + (size_t)m * DM + nn) =
                    make_float4(acc[i][j][0] + bv.x, acc[i][j][1] + bv.y,
                                acc[i][j][2] + bv.z, acc[i][j][3] + bv.w);
            }
        }
    }
}

// ---------------- V transpose: Vn[b,h,l,64] -> Vt[b,h,d,512] (bf16) ----------------
__global__ __launch_bounds__(256) void vtrans_kernel(const __bf16* __restrict__ Vn,
                                                     __bf16* __restrict__ Vt) {
    __shared__ __bf16 Ts[64][72];
    int bh = blockIdx.x >> 3, lt = blockIdx.x & 7;
    const __bf16* src = Vn + ((size_t)bh * LL + lt * 64) * 64;
    int r = threadIdx.x >> 2, s = threadIdx.x & 3;
    *(bf16x8*)&Ts[r][s * 16]     = *(const bf16x8*)(src + r * 64 + s * 16);
    *(bf16x8*)&Ts[r][s * 16 + 8] = *(const bf16x8*)(src + r * 64 + s * 16 + 8);
    __syncthreads();
    __bf16* dst = Vt + ((size_t)bh * 64 + r) * LL + lt * 64 + s * 16;
    bf16x8 a, bvv;
#pragma unroll
    for (int e = 0; e < 8; ++e) { a[e] = Ts[s * 16 + e][r]; bvv[e] = Ts[s * 16 + 8 + e][r]; }
    *(bf16x8*)dst = a;
    *(bf16x8*)(dst + 8) = bvv;
}

// ---------------- relative sinusoidal PE table [512][64] ----------------
__global__ __launch_bounds__(256) void pe_kernel(float* __restrict__ PE) {
    int idx = blockIdx.x * 256 + threadIdx.x;
    int l = idx >> 6, d = idx & 63;
    float p = (float)(l - LL / 2);
    const float cexp = -9.210340371976184f / 31.0f;
    float val;
    if (d < 32) { float f = expf((float)d * cexp);        val = sinf(p * f); }
    else        { float f = expf((float)(d - 32) * cexp); val = cosf(p * f); }
    PE[idx] = val;
}

// ---------------- pos projection -> bf16 cols 64..127 of Qc/K1c/K2c, all 8 b ----------------
__global__ __launch_bounds__(256) void posproj_kernel(
    const float* __restrict__ PE, const float* __restrict__ Wp,
    __bf16* __restrict__ Qc, __bf16* __restrict__ K1c, __bf16* __restrict__ K2c)
{
    int idx = blockIdx.x * 256 + threadIdx.x;   // 512*3072
    int l = idx / 3072, e = idx - l * 3072;
    int c = e >> 10, h = (e >> 6) & 15, d = e & 63;
    const float4* pe4 = (const float4*)(PE + (size_t)l * 64);
    const float4* w4  = (const float4*)(Wp + (size_t)e * 64);
    float acc = 0.f;
#pragma unroll
    for (int k = 0; k < 16; ++k) fma4(acc, pe4[k], w4[k]);
    __bf16 bv = (__bf16)acc;
    __bf16* T = (c == 0) ? Qc : (c == 1) ? K1c : K2c;
    size_t off = ((size_t)h * LL + l) * 128 + 64 + d;
#pragma unroll
    for (int b = 0; b < 8; ++b) T[(size_t)b * (HN * LL * 128) + off] = bv;
}

// ---------------- MFMA flash attention ----------------
__global__ __launch_bounds__(256) void attn_kernel(
    const __bf16* __restrict__ Qc, const __bf16* __restrict__ K1c,
    const __bf16* __restrict__ K2c, const __bf16* __restrict__ Vt,
    const int* __restrict__ maskp, const int* __restrict__ qmask,
    const float* __restrict__ shiftp, const float* __restrict__ biasp,
    __bf16* __restrict__ AO)
{
    __shared__ __bf16 K1s[64 * 136];
    __shared__ __bf16 K2s[64 * 136];
    __shared__ __bf16 Vts[64 * 72];
    __shared__ __bf16 Sb[4 * 16 * 72];

    const int tid = threadIdx.x;
    const int lane = tid & 63;
    const int wid = tid >> 6;
    const int fr = lane & 15;
    const int fq = lane >> 4;

    const int qt = blockIdx.x & 3;
    const int h  = (blockIdx.x >> 2) & 15;
    const int b  = blockIdx.x >> 6;
    const int q0w = qt * 128 + wid * 32;
    const size_t bh = (size_t)(b * HN + h);

    const float sft = shiftp[0], bia = biasp[0];

    bf16x8 qf[2][4];
#pragma unroll
    for (int jq = 0; jq < 2; ++jq)
#pragma unroll
        for (int kf = 0; kf < 4; ++kf)
            qf[jq][kf] = *(const bf16x8*)(Qc + (bh * LL + q0w + jq * 16 + fr) * 128 + kf * 32 + fq * 8);

    const int qmI[2] = { qmask[b * LL + q0w + fr], qmask[b * LL + q0w + 16 + fr] };
    const float qgf[2] = { (float)(q0w + fr), (float)(q0w + 16 + fr) };

    float mrun[2] = { -1e30f, -1e30f };
    float lrun[2] = { 0.f, 0.f };
    f32x4 ot[4][2] = {};

    const __bf16* K1g0 = K1c + bh * LL * 128;
    const __bf16* K2g0 = K2c + bh * LL * 128;
    const __bf16* Vtg0 = Vt + bh * 64 * LL;
    __bf16* Sw = Sb + wid * 16 * 72;

    for (int t = 0; t < 8; ++t) {
        const int j0 = t * 64;
        const __bf16* K1g = K1g0 + (size_t)j0 * 128;
        const __bf16* K2g = K2g0 + (size_t)j0 * 128;
#pragma unroll
        for (int p = 0; p < 4; ++p) {
            int idx = p * 256 + tid, rr = idx >> 4, u = idx & 15;
            *(bf16x8*)(K1s + rr * 136 + u * 8) = *(const bf16x8*)(K1g + rr * 128 + u * 8);
            *(bf16x8*)(K2s + rr * 136 + u * 8) = *(const bf16x8*)(K2g + rr * 128 + u * 8);
        }
#pragma unroll
        for (int p = 0; p < 2; ++p) {
            int idx = p * 256 + tid, rr = idx >> 3, u = idx & 7;
            *(bf16x8*)(Vts + rr * 72 + u * 8) = *(const bf16x8*)(Vtg0 + (size_t)rr * LL + j0 + u * 8);
        }
        unsigned long long qbits = __ballot(qmask[b * LL + j0 + lane] != 0);
        unsigned long long kbits = __ballot(maskp[b * LL + j0 + lane] != 0);
        __syncthreads();

        // ---- QK^T (self) ----
        f32x4 accS[4][2] = {};
        __builtin_amdgcn_s_setprio(1);
#pragma unroll
        for (int kb = 0; kb < 4; ++kb) {
            bf16x8 af[4];
#pragma unroll
            for (int kf = 0; kf < 4; ++kf)
                af[kf] = *(const bf16x8*)(K1s + (kb * 16 + fr) * 136 + kf * 32 + fq * 8);
#pragma unroll
            for (int kf = 0; kf < 4; ++kf) {
                accS[kb][0] = __builtin_amdgcn_mfma_f32_16x16x32_bf16(af[kf], qf[0][kf], accS[kb][0], 0, 0, 0);
                accS[kb][1] = __builtin_amdgcn_mfma_f32_16x16x32_bf16(af[kf], qf[1][kf], accS[kb][1], 0, 0, 0);
            }
        }
        __builtin_amdgcn_s_setprio(0);
        // ---- QK^T (other) + fused select/gaussian/mask ----
#pragma unroll
        for (int kb = 0; kb < 4; ++kb) {
            bf16x8 af[4];
#pragma unroll
            for (int kf = 0; kf < 4; ++kf)
                af[kf] = *(const bf16x8*)(K2s + (kb * 16 + fr) * 136 + kf * 32 + fq * 8);
            f32x4 accO[2] = {};
            __builtin_amdgcn_s_setprio(1);
#pragma unroll
            for (int kf = 0; kf < 4; ++kf) {
                accO[0] = __builtin_amdgcn_mfma_f32_16x16x32_bf16(af[kf], qf[0][kf], accO[0], 0, 0, 0);
                accO[1] = __builtin_amdgcn_mfma_f32_16x16x32_bf16(af[kf], qf[1][kf], accO[1], 0, 0, 0);
            }
            __builtin_amdgcn_s_setprio(0);
#pragma unroll
            for (int jq = 0; jq < 2; ++jq)
#pragma unroll
                for (int r = 0; r < 4; ++r) {
                    int ko = kb * 16 + fq * 4 + r;
                    float v = (((int)(qbits >> ko) & 1) == qmI[jq]) ? accS[kb][jq][r] : accO[jq][r];
                    float di = qgf[jq] - (float)(j0 + ko);
                    v = v - fmaf(sft, di * di, bia);
                    accS[kb][jq][r] = ((int)(kbits >> ko) & 1) ? v : -1e30f;
                }
        }

        // ---- online softmax (q lane-local) ----
        float mn0 = mrun[0], mn1 = mrun[1];
#pragma unroll
        for (int kb = 0; kb < 4; ++kb)
#pragma unroll
            for (int r = 0; r < 4; ++r) {
                mn0 = fmaxf(mn0, accS[kb][0][r]);
                mn1 = fmaxf(mn1, accS[kb][1][r]);
            }
        mn0 = fmaxf(mn0, __shfl_xor(mn0, 16)); mn0 = fmaxf(mn0, __shfl_xor(mn0, 32));
        mn1 = fmaxf(mn1, __shfl_xor(mn1, 16)); mn1 = fmaxf(mn1, __shfl_xor(mn1, 32));
        float sc0 = __expf(mrun[0] - mn0), sc1 = __expf(mrun[1] - mn1);
        mrun[0] = mn0; mrun[1] = mn1;
        float sum0 = 0.f, sum1 = 0.f;
#pragma unroll
        for (int kb = 0; kb < 4; ++kb)
#pragma unroll
            for (int r = 0; r < 4; ++r) {
                float p0 = __expf(accS[kb][0][r] - mn0);
                float p1 = __expf(accS[kb][1][r] - mn1);
                accS[kb][0][r] = p0; accS[kb][1][r] = p1;
                sum0 += p0; sum1 += p1;
            }
        sum0 += __shfl_xor(sum0, 16); sum0 += __shfl_xor(sum0, 32);
        sum1 += __shfl_xor(sum1, 16); sum1 += __shfl_xor(sum1, 32);
        lrun[0] = lrun[0] * sc0 + sum0;
        lrun[1] = lrun[1] * sc1 + sum1;
#pragma unroll
        for (int fd = 0; fd < 4; ++fd)
#pragma unroll
            for (int r = 0; r < 4; ++r) { ot[fd][0][r] *= sc0; ot[fd][1][r] *= sc1; }

        // ---- PV: O^T += mfma(Vt, P) ----
        bf16x8 vtf[4][2];
#pragma unroll
        for (int fd = 0; fd < 4; ++fd)
#pragma unroll
            for (int kf = 0; kf < 2; ++kf)
                vtf[fd][kf] = *(const bf16x8*)(Vts + (fd * 16 + fr) * 72 + kf * 32 + fq * 8);
#pragma unroll
        for (int jq = 0; jq < 2; ++jq) {
#pragma unroll
            for (int kb = 0; kb < 4; ++kb) {
                bf16x4 pk;
#pragma unroll
                for (int r = 0; r < 4; ++r) pk[r] = (__bf16)accS[kb][jq][r];
                *(bf16x4*)(Sw + fr * 72 + kb * 16 + fq * 4) = pk;
            }
            bf16x8 pf0 = *(const bf16x8*)(Sw + fr * 72 + fq * 8);
            bf16x8 pf1 = *(const bf16x8*)(Sw + fr * 72 + 32 + fq * 8);
            __builtin_amdgcn_s_setprio(1);
#pragma unroll
            for (int fd = 0; fd < 4; ++fd) {
                ot[fd][jq] = __builtin_amdgcn_mfma_f32_16x16x32_bf16(vtf[fd][0], pf0, ot[fd][jq], 0, 0, 0);
                ot[fd][jq] = __builtin_amdgcn_mfma_f32_16x16x32_bf16(vtf[fd][1], pf1, ot[fd][jq], 0, 0, 0);
            }
            __builtin_amdgcn_s_setprio(0);
        }
        __syncthreads();
    }

#pragma unroll
    for (int jq = 0; jq < 2; ++jq) {
        float inv = 1.0f / lrun[jq];
        int q = q0w + jq * 16 + fr;
        __bf16* dst = AO + ((size_t)(b * LL + q)) * DM + h * 64;
#pragma unroll
        for (int fd = 0; fd < 4; ++fd) {
            bf16x4 o;
#pragma unroll
            for (int r = 0; r < 4; ++r) o[r] = (__bf16)(ot[fd][jq][r] * inv);
            *(bf16x4*)(dst + fd * 16 + fq * 4) = o;
        }
    }
}

extern "C" void kernel_launch(void* const* d_in, const int* in_sizes, int n_in,
                              void* d_out, int out_size, void* d_ws, size_t ws_size,
                              hipStream_t stream) {
    const float* x     = (const float*)d_in[0];
    const int*   mask  = (const int*)d_in[1];
    const int*   qmask = (const int*)d_in[2];
    const float* W_qkv = (const float*)d_in[3];
    const float* W_pos = (const float*)d_in[4];
    const float* W_fc  = (const float*)d_in[5];
    const float* b_fc  = (const float*)d_in[6];
    const float* shift = (const float*)d_in[7];
    const float* bias  = (const float*)d_in[8];
    float* out = (float*)d_out;

    __bf16* Qcb  = (__bf16*)d_ws;           // [8,16,512,128]
    __bf16* K1cb = Qcb  + 8388608;
    __bf16* K2cb = K1cb + 8388608;
    __bf16* Vnb  = K2cb + 8388608;          // [8,16,512,64]
    __bf16* Vtb  = Vnb  + 4194304;          // [8,16,64,512]
    __bf16* Xb   = Vtb  + 4194304;          // [4096,1024]
    __bf16* Wqkvb = Xb  + 4194304;          // [4096,1024] remapped
    __bf16* Wfcb  = Wqkvb;                  // alias (cvt after gemm0)
    __bf16* AOb   = Xb;                     // alias (attn after gemm0)
    float*  PEw   = (float*)(Wqkvb + 4194304);  // [512,64] f32

    cvt_kernel<<<2048, 256, 0, stream>>>(x, Xb, 524288);
    cvt_kernel<<<512, 256, 0, stream>>>(W_qkv, Wqkvb, 131072);
    cvt_kernel<<<1536, 256, 0, stream>>>(W_qkv + 2097152, Wqkvb + 1048576, 393216);
    gemm_mfma<0><<<dim3(32, 32), 256, 0, stream>>>(Xb, Wqkvb, Qcb, K1cb, K2cb, Vnb,
                                                   nullptr, nullptr, 1024);
    vtrans_kernel<<<1024, 256, 0, stream>>>(Vnb, Vtb);
    cvt_kernel<<<512, 256, 0, stream>>>(W_fc, Wfcb, 131072);
    pe_kernel<<<128, 256, 0, stream>>>(PEw);
    posproj_kernel<<<6144, 256, 0, stream>>>(PEw, W_pos, Qcb, K1cb, K2cb);
    attn_kernel<<<512, 256, 0, stream>>>(Qcb, K1cb, K2cb, Vtb, mask, qmask,
                                         shift, bias, AOb);
    gemm_mfma<1><<<dim3(8, 32), 256, 0, stream>>>(AOb, Wfcb, nullptr, nullptr, nullptr,
                                                  nullptr, out, b_fc, 1024);
}